// Round 8
// baseline (57.217 us; speedup 1.0000x reference)
//
#include <hip/hip_runtime.h>
#include <hip/hip_bf16.h>

// WaveletConv: Haar DWT -> 4x (64x64 channel mix) -> inverse Haar, fused.
// B=8, C=64, H=256, W=256. Subband grid 128x128.
// R8: full-W tiles with K-split. Tile = 32 ch x 2 rows x 256 w f32 (64KB),
//     every DMA = 1KB contiguous (full DRAM row, single open); K=64 GEMM
//     split over 2 khalf steps with carried accumulators; epilogue writes
//     full output rows per h-pair. 2 LDS buffers, depth-1 prefetch, exact
//     store-exclusion vmcnt ledger, 1 block/CU x 8 waves.

using bf16x8 = __attribute__((ext_vector_type(8))) short;   // 8 bf16
using f32x4  = __attribute__((ext_vector_type(4))) float;   // MFMA acc
using f32x2  = __attribute__((ext_vector_type(2))) float;

__device__ inline unsigned short f2bf(float v) {
    __hip_bfloat16 h = __float2bfloat16(v);
    return __builtin_bit_cast(unsigned short, h);
}

// ---------------------------------------------------------------------------
// Prep kernel (64 blocks x 256 thr): bake per-lane MFMA A-fragments (scaled
// by 0.5 = Haar factor) and combined biases into d_ws.
//   afrag[((band*2+ks)*4+mt)*512 + lane*8 + i] =
//       bf16( 0.5 * W_band[o=16*mt+(lane&15)][c=32*ks+(lane>>4)*8+i] )
//   bcomb[d*64+o] = 0.5*(bLL + sH*bLH + sW*bHL + sH*sW*bHH), d=di*2+dj
// ---------------------------------------------------------------------------
__global__ __launch_bounds__(256) void wvc_prep(
    const float* __restrict__ wLL, const float* __restrict__ bLL,
    const float* __restrict__ wLH, const float* __restrict__ bLH,
    const float* __restrict__ wHL, const float* __restrict__ bHL,
    const float* __restrict__ wHH, const float* __restrict__ bHH,
    unsigned short* __restrict__ afrag, float* __restrict__ bcomb)
{
    const int idx  = blockIdx.x * 256 + threadIdx.x;  // 0..16383
    const int i    = idx & 7;
    const int lane = (idx >> 3) & 63;
    const int mt   = (idx >> 9) & 3;
    const int ks   = (idx >> 11) & 1;
    const int band = (idx >> 12) & 3;
    const float* Ws[4] = {wLL, wLH, wHL, wHH};
    const int o = mt * 16 + (lane & 15);
    const int c = ks * 32 + (lane >> 4) * 8 + i;
    afrag[idx] = f2bf(0.5f * Ws[band][o * 64 + c]);

    if (blockIdx.x == 0 && threadIdx.x < 64) {
        const int t = threadIdx.x;
        float b0 = bLL[t], b1 = bLH[t], b2 = bHL[t], b3 = bHH[t];
        bcomb[0 * 64 + t] = 0.5f * (b0 + b1 + b2 + b3);
        bcomb[1 * 64 + t] = 0.5f * (b0 + b1 - b2 - b3);
        bcomb[2 * 64 + t] = 0.5f * (b0 - b1 + b2 - b3);
        bcomb[3 * 64 + t] = 0.5f * (b0 - b1 - b2 + b3);
    }
}

// ---------------------------------------------------------------------------
// Main kernel. grid = 256 blocks, 512 threads (8 waves), 1 block/CU.
// Block blk: b = blk>>5, ihg = blk&31 -> 4 h-pairs hp = ihg*4+(t>>1).
// Steps t=0..7: kh = t&1 stages channels kh*32..+31, full W, rows h0,h0+1.
// LDS tile: off(ch_l,row,w) = ch_l*2048 + (ch_l>>3)*64 + row*1024 + w*4.
// Wave wv: sgp = wv>>1 (sites sgp*32..+31), mth = wv&1 (out-ch mt=2mth,2mth+1).
// Per step per wave: 8 DMAs (1KB each), 32 ds_read_b64, 16 MFMAs;
// epilogue at kh==1: 32 nt f32x2 stores.
// vmcnt ledger (DMA=8, stores=32): t=0 ->8; t even ->40; t odd<7 ->8; t=7 ->0.
// ---------------------------------------------------------------------------
#define NT 8
__global__ __launch_bounds__(512, 1) void wvc_main(
    const float* __restrict__ x,
    const unsigned short* __restrict__ afrag_g,
    const float* __restrict__ bcomb,
    float* __restrict__ out)
{
    __shared__ __align__(64) unsigned char lds_x[2][65792];  // 64KB + pads
    __shared__ __align__(16) float lds_bc[256];

    const int tid = threadIdx.x;
    const int l   = tid & 63;
    const int wv  = tid >> 6;          // 0..7
    const int blk = blockIdx.x;
    const int b   = blk >> 5;
    const int ihg = blk & 31;

    const int sgp   = wv >> 1;         // 0..3: sites sgp*32 .. sgp*32+31
    const int mth   = wv & 1;          // mt = 2*mth, 2*mth+1
    const int lg    = l >> 4;
    const int sbase = sgp * 32 + (l & 15);

    if (tid < 256) lds_bc[tid] = bcomb[tid];

    // ---- A-fragments: all (band, kh, mtl) in registers (16 x bf16x8) ----
    const unsigned short* afb = afrag_g + (size_t)l * 8;
    bf16x8 a[4][2][2];  // [band][kh][mtl]
    #pragma unroll
    for (int bd = 0; bd < 4; ++bd)
        #pragma unroll
        for (int kh = 0; kh < 2; ++kh)
            #pragma unroll
            for (int mtl = 0; mtl < 2; ++mtl)
                a[bd][kh][mtl] = *(const bf16x8*)(
                    afb + (size_t)((bd * 2 + kh) * 4 + 2 * mth + mtl) * 512);

    // per-lane global w offset (16B per lane => 1KB per DMA)
    const float* xbase = x + (size_t)b * 4194304 + (size_t)l * 4;

    // stage step s: channels (s&1)*32 + wv*4 + (k>>1), row k&1, full W
    #define STAGE(s)                                                          \
    {                                                                         \
        unsigned char* lb = &lds_x[(s) & 1][0];                               \
        const int kh_ = (s) & 1;                                              \
        const int h0_ = 8 * ihg + 2 * ((s) >> 1);                             \
        _Pragma("unroll")                                                     \
        for (int k = 0; k < 8; ++k) {                                         \
            const int chl = wv * 4 + (k >> 1);                                \
            const float* g = xbase + (size_t)(kh_ * 32 + chl) * 65536         \
                                   + (size_t)(h0_ + (k & 1)) * 256;           \
            __builtin_amdgcn_global_load_lds(                                 \
                (const __attribute__((address_space(1))) void*)g,             \
                (__attribute__((address_space(3))) void*)(                    \
                    lb + chl * 2048 + (chl >> 3) * 64 + (k & 1) * 1024        \
                       + l * 16),                                             \
                16, 0, 0);                                                    \
        }                                                                     \
    }

    STAGE(0);
    asm volatile("s_waitcnt lgkmcnt(0)" ::: "memory");  // lds_bc visible

    f32x4 acc[2][2][4];  // [sgq][mtl][band], carried across kh=0,1

    #pragma unroll
    for (int t = 0; t < NT; ++t) {
        const int kh = t & 1;
        if (t + 1 < NT) STAGE(t + 1);
        // ledger: queue at wait = [DMA(t)=8][stores(t-1)=32 if t even>0]
        //                         [DMA(t+1)=8 if t+1<NT]; older stores drain.
        if (t == 0)        asm volatile("s_waitcnt vmcnt(8)"  ::: "memory");
        else if (kh == 0)  asm volatile("s_waitcnt vmcnt(40)" ::: "memory");
        else if (t < NT-1) asm volatile("s_waitcnt vmcnt(8)"  ::: "memory");
        else               asm volatile("s_waitcnt vmcnt(0)"  ::: "memory");
        __builtin_amdgcn_sched_barrier(0);
        __builtin_amdgcn_s_barrier();      // raw: prefetch stays in flight
        __builtin_amdgcn_sched_barrier(0);

        const unsigned char* bx = lds_x[kh];

        if (kh == 0) {
            #pragma unroll
            for (int sgq = 0; sgq < 2; ++sgq)
                #pragma unroll
                for (int mtl = 0; mtl < 2; ++mtl)
                    #pragma unroll
                    for (int bd = 0; bd < 4; ++bd)
                        acc[sgq][mtl][bd] = (f32x4){0.f, 0.f, 0.f, 0.f};
        }

        // ---- per site-group: patches -> Haar -> B-frags -> MFMA ----
        #pragma unroll
        for (int sgq = 0; sgq < 2; ++sgq) {
            const int site = sbase + sgq * 16;
            float2 p0[8], p1[8];
            #pragma unroll
            for (int i = 0; i < 8; ++i) {
                const unsigned char* base =
                    bx + (size_t)(lg * 8 + i) * 2048 + lg * 64 + site * 8;
                p0[i] = *(const float2*)(base);          // row h0
                p1[i] = *(const float2*)(base + 1024);   // row h0+1
            }
            bf16x8 bfr[4];
            #pragma unroll
            for (int i = 0; i < 8; ++i) {
                float aa = p0[i].x + p0[i].y, mm = p0[i].x - p0[i].y;
                float cc = p1[i].x + p1[i].y, dd = p1[i].x - p1[i].y;
                bfr[0][i] = (short)f2bf(aa + cc);
                bfr[1][i] = (short)f2bf(aa - cc);
                bfr[2][i] = (short)f2bf(mm + dd);
                bfr[3][i] = (short)f2bf(mm - dd);
            }
            #pragma unroll
            for (int bd = 0; bd < 4; ++bd)
                #pragma unroll
                for (int mtl = 0; mtl < 2; ++mtl)
                    acc[sgq][mtl][bd] = __builtin_amdgcn_mfma_f32_16x16x32_bf16(
                        a[bd][kh][mtl], bfr[bd], acc[sgq][mtl][bd], 0, 0, 0);
        }

        // ---- epilogue every 2nd step: inverse Haar + bias, nt stores ----
        if (kh == 1) {
            const int h0 = 8 * ihg + 2 * (t >> 1);
            #pragma unroll
            for (int sgq = 0; sgq < 2; ++sgq) {
                const int site = sbase + sgq * 16;
                float* ob = out + (size_t)b * 4194304 + (size_t)h0 * 256
                                + 2 * site;
                #pragma unroll
                for (int mtl = 0; mtl < 2; ++mtl) {
                    const int ob0 = (2 * mth + mtl) * 16 + lg * 4;
                    f32x4 bc0 = *(const f32x4*)(&lds_bc[  0 + ob0]);
                    f32x4 bc1 = *(const f32x4*)(&lds_bc[ 64 + ob0]);
                    f32x4 bc2 = *(const f32x4*)(&lds_bc[128 + ob0]);
                    f32x4 bc3 = *(const f32x4*)(&lds_bc[192 + ob0]);
                    #pragma unroll
                    for (int r = 0; r < 4; ++r) {
                        float y0 = acc[sgq][mtl][0][r];  // LL
                        float y1 = acc[sgq][mtl][1][r];  // LH (high-H)
                        float y2 = acc[sgq][mtl][2][r];  // HL (high-W)
                        float y3 = acc[sgq][mtl][3][r];  // HH
                        float s01 = y0 + y1, d01 = y0 - y1;
                        float s23 = y2 + y3, d23 = y2 - y3;
                        f32x2 v0; v0[0] = 0.5f * (s01 + s23) + bc0[r];
                                  v0[1] = 0.5f * (s01 - s23) + bc1[r];
                        f32x2 v1; v1[0] = 0.5f * (d01 + d23) + bc2[r];
                                  v1[1] = 0.5f * (d01 - d23) + bc3[r];
                        float* po = ob + (size_t)(ob0 + r) * 65536;
                        __builtin_nontemporal_store(v0, (f32x2*)po);
                        __builtin_nontemporal_store(v1, (f32x2*)(po + 256));
                    }
                }
            }
        }

        __builtin_amdgcn_sched_barrier(0);
        __builtin_amdgcn_s_barrier();   // all waves done with buf[kh] before
        __builtin_amdgcn_sched_barrier(0);  // step t+1 stages over it
    }
    #undef STAGE
}

extern "C" void kernel_launch(void* const* d_in, const int* in_sizes, int n_in,
                              void* d_out, int out_size, void* d_ws, size_t ws_size,
                              hipStream_t stream) {
    const float* x   = (const float*)d_in[0];
    const float* wLL = (const float*)d_in[1];
    const float* bLL = (const float*)d_in[2];
    const float* wLH = (const float*)d_in[3];
    const float* bLH = (const float*)d_in[4];
    const float* wHL = (const float*)d_in[5];
    const float* bHL = (const float*)d_in[6];
    const float* wHH = (const float*)d_in[7];
    const float* bHH = (const float*)d_in[8];
    float* out = (float*)d_out;

    unsigned short* afrag = (unsigned short*)d_ws;   // 32768 B
    float* bcomb = (float*)((char*)d_ws + 32768);    // 1024 B

    wvc_prep<<<64, 256, 0, stream>>>(wLL, bLL, wLH, bLH, wHL, bHL, wHH, bHH,
                                     afrag, bcomb);
    wvc_main<<<256, 512, 0, stream>>>(x, afrag, bcomb, out);
}